// Round 1
// 10901.208 us; speedup vs baseline: 2.9388x; 2.9388x over previous
//
#include <hip/hip_runtime.h>

// LSTMx: 2-layer LSTM, L=512, N=64, IN=256, H=1024. fp32 in/out, bf16 MFMA compute.
// Structure: 3 prep kernels + one persistent kernel (256 blocks = 1/CU via 137KB LDS)
// doing the layer-pipelined recurrence with a relaxed two-level grid barrier.
//
// R1 change vs. 32.0ms baseline: removed ALL bulk cache-maintenance from the steady
// state (__threadfence / ACQ_REL atomics -> buffer_wbl2+buffer_inv full-L2 walks each
// step was the theory for ~50 of the 62us/step). h propagation now uses explicit
// coherence-point accesses: stores `global_store_dword sc0 sc1` (write-through),
// K-loop A loads `global_load_dwordx4 sc0 sc1` (L2-bypass). Barrier = relaxed
// monotonic atomics + explicit vmcnt(0) drain. K-loop is compile-time unrolled with
// hand-counted vmcnt waits, prefetch depth 10 (asm loads are invisible to compiler
// waitcnt insertion; sched_barrier(0) after each wait per ISA-guide rule #18).

typedef unsigned short u16;
typedef unsigned int u32;
typedef __attribute__((ext_vector_type(8))) short short8;
typedef __attribute__((ext_vector_type(4))) float float4v;
typedef __attribute__((ext_vector_type(4))) int int4v;

// ---- workspace layout (bytes) ----
#define WP0_OFF   0u               // 128*32*1280*2 = 10485760  (layer0 packed W, bf16)
#define WP1_OFF   10485760u        // 128*32*2048*2 = 16777216  (layer1 packed W)
#define XB_OFF    27262976u        // 512*64*256*2  = 16777216  (x in bf16)
#define HB0_OFF   44040192u        // 2*64*1024*2   = 262144    (h0 double buffer, bf16)
#define HB1_OFF   44302336u        // 2*64*1024*2
#define BC0_OFF   44564480u        // 4096*4  (b_ih0+b_hh0)
#define BC1_OFF   44580864u        // 4096*4
#define BAR_OFF   44597248u        // 1024*4  (grid barrier state)

// ---- output offsets (floats) ----
#define OUT_Y_OFF 0
#define ALLC_OFF  33554432
#define HN_OFF    100663296
#define CN_OFF    100794368

// LDS: W slice (max 32 rows * (2048+8) * 2B = 131584) + gate scratch 64*33*4 = 8448
#define SC_BYTE_OFF 131584
#define LDS_BYTES   140032

__device__ inline u16 f2b(float v) {  // fp32 -> bf16 RTNE (finite inputs)
  union { float f; unsigned u; } a; a.f = v;
  unsigned r = a.u + 0x7FFFu + ((a.u >> 16) & 1u);
  return (u16)(r >> 16);
}

__device__ inline float sigf(float x) { return 1.0f / (1.0f + __expf(-x)); }
__device__ inline float tanh_fast(float x) { return 1.0f - 2.0f / (1.0f + __expf(2.0f * x)); }

// Coherence-point (L1+L2 bypass) 16B load / 4B store.
__device__ __attribute__((always_inline)) inline short8 ldg_sc(const u16* p) {
  short8 r;
  asm volatile("global_load_dwordx4 %0, %1, off sc0 sc1" : "=v"(r) : "v"(p));
  return r;
}
__device__ __attribute__((always_inline)) inline void stg_sc(u32* p, u32 v) {
  asm volatile("global_store_dword %0, %1, off sc0 sc1" : : "v"(p), "v"(v) : "memory");
}

template<int N>
__device__ __attribute__((always_inline)) inline void wait_vm() {
  static_assert(N % 4 == 0 && N >= 0 && N <= 36, "bad vmcnt");
  if constexpr (N == 0)  asm volatile("s_waitcnt vmcnt(0)" ::: "memory");
  if constexpr (N == 4)  asm volatile("s_waitcnt vmcnt(4)" ::: "memory");
  if constexpr (N == 8)  asm volatile("s_waitcnt vmcnt(8)" ::: "memory");
  if constexpr (N == 12) asm volatile("s_waitcnt vmcnt(12)" ::: "memory");
  if constexpr (N == 16) asm volatile("s_waitcnt vmcnt(16)" ::: "memory");
  if constexpr (N == 20) asm volatile("s_waitcnt vmcnt(20)" ::: "memory");
  if constexpr (N == 24) asm volatile("s_waitcnt vmcnt(24)" ::: "memory");
  if constexpr (N == 28) asm volatile("s_waitcnt vmcnt(28)" ::: "memory");
  if constexpr (N == 32) asm volatile("s_waitcnt vmcnt(32)" ::: "memory");
  if constexpr (N == 36) asm volatile("s_waitcnt vmcnt(36)" ::: "memory");
}

// ---------------- prep kernels ----------------

__global__ void pack_w0(const float* __restrict__ w_ih, const float* __restrict__ w_hh,
                        u16* __restrict__ wp) {
  int k = blockIdx.x * 256 + threadIdx.x;   // 0..1279
  int q = blockIdx.y;                       // 0..31
  int b = blockIdx.z;                       // 0..127
  int g = q >> 3, jj = q & 7;
  int r = g * 1024 + b * 8 + jj;
  float v = (k < 256) ? w_ih[r * 256 + k] : w_hh[r * 1024 + (k - 256)];
  wp[(b * 32 + q) * 1280 + k] = f2b(v);
}

__global__ void pack_w1(const float* __restrict__ w_ih, const float* __restrict__ w_hh,
                        u16* __restrict__ wp) {
  int k = blockIdx.x * 256 + threadIdx.x;   // 0..2047
  int q = blockIdx.y;
  int b = blockIdx.z;
  int g = q >> 3, jj = q & 7;
  int r = g * 1024 + b * 8 + jj;
  float v = (k < 1024) ? w_ih[r * 1024 + k] : w_hh[r * 1024 + (k - 1024)];
  wp[(b * 32 + q) * 2048 + k] = f2b(v);
}

__global__ void prep_misc(const float* __restrict__ x, const float* __restrict__ h0,
                          const float* __restrict__ bih0, const float* __restrict__ bhh0,
                          const float* __restrict__ bih1, const float* __restrict__ bhh1,
                          u16* __restrict__ xb, u16* __restrict__ hb0, u16* __restrict__ hb1,
                          float* __restrict__ bc0, float* __restrict__ bc1,
                          unsigned* __restrict__ bar) {
  int i = blockIdx.x * 256 + threadIdx.x;
  if (i < 8388608) { xb[i] = f2b(x[i]); return; }
  i -= 8388608;
  if (i < 65536) { hb0[i] = f2b(h0[i]); return; }
  i -= 65536;
  if (i < 65536) { hb1[i] = f2b(h0[65536 + i]); return; }
  i -= 65536;
  if (i < 4096) { bc0[i] = bih0[i] + bhh0[i]; return; }
  i -= 4096;
  if (i < 4096) { bc1[i] = bih1[i] + bhh1[i]; return; }
  i -= 4096;
  if (i < 1024) bar[i] = 0u;
}

// ---------------- grid barrier ----------------
// All-RELAXED, monotonic (no resets -> no reset/arrival race). No fences: h data is
// already at the coherence point (sc0 sc1 stores, drained by the explicit vmcnt(0)
// before s_barrier), and all consumers read it with coherence-point loads, so no
// cache can hold stale h. Atomics only provide arrival counting.
__device__ inline void grid_barrier(unsigned* __restrict__ bar, int gi) {
  asm volatile("s_waitcnt vmcnt(0)" ::: "memory");   // each wave drains its own stores
  __syncthreads();
  if (threadIdx.x == 0) {
    unsigned* gen = bar + 576;  // own cacheline
    unsigned g = __hip_atomic_load(gen, __ATOMIC_RELAXED, __HIP_MEMORY_SCOPE_AGENT);
    unsigned a = __hip_atomic_fetch_add(bar + gi * 32, 1u, __ATOMIC_RELAXED, __HIP_MEMORY_SCOPE_AGENT);
    bool flipped = false;
    if ((a & 15u) == 15u) {
      unsigned r = __hip_atomic_fetch_add(bar + 512, 1u, __ATOMIC_RELAXED, __HIP_MEMORY_SCOPE_AGENT);
      if ((r & 15u) == 15u) {
        __hip_atomic_store(gen, g + 1u, __ATOMIC_RELAXED, __HIP_MEMORY_SCOPE_AGENT);
        flipped = true;
      }
    }
    if (!flipped) {
      while (__hip_atomic_load(gen, __ATOMIC_RELAXED, __HIP_MEMORY_SCOPE_AGENT) == g)
        __builtin_amdgcn_s_sleep(2);
    }
  }
  __syncthreads();
  asm volatile("" ::: "memory");
}

// ---------------- per-step GEMM K-loop ----------------
// Wave wv owns k-quarter [wv*KQ, (wv+1)*KQ) (units of 32), computes all 8 MFMA tiles.
// A via coherence-point asm loads, PF-deep register pipeline with hand vmcnt waits.
// B from LDS-resident W slice. Fully compile-time unrolled (kstep recursion) so every
// vmcnt literal and array index is constant.
template<int KQ, int SW, int PF, int KS>
__device__ __attribute__((always_inline)) inline
void kstep(const u16* __restrict__ pA, const u16* __restrict__ pB,
           const int4v& offA, const int4v& offB, const u16* __restrict__ Wl,
           int brow0, int brow1, int base, short8 (&as)[PF][4], float4v (&acc)[4][2]) {
  if constexpr (KS < KQ) {
    const int gks = base + KS;
    // LDS B reads issued BEFORE the vm wait so ds latency overlaps it.
    short8 b0 = *(const short8*)&Wl[brow0 + gks * 32];
    short8 b1 = *(const short8*)&Wl[brow1 + gks * 32];
    constexpr int REM = KQ - 1 - KS;
    constexpr int W = 4 * (REM < (PF - 1) ? REM : (PF - 1));
    wait_vm<W>();                          // iteration-KS A loads complete (in-order vmcnt)
    __builtin_amdgcn_sched_barrier(0);     // rule #18: stop MFMA hoisting past the wait
#pragma unroll
    for (int mt = 0; mt < 4; ++mt) {
      acc[mt][0] = __builtin_amdgcn_mfma_f32_16x16x32_bf16(as[KS % PF][mt], b0, acc[mt][0], 0, 0, 0);
      acc[mt][1] = __builtin_amdgcn_mfma_f32_16x16x32_bf16(as[KS % PF][mt], b1, acc[mt][1], 0, 0, 0);
    }
    if constexpr (KS + PF < KQ) {
      const int gn = base + KS + PF;
#pragma unroll
      for (int mt = 0; mt < 4; ++mt) {
        const u16* ap = (gn < SW) ? (pA + offA[mt] + gn * 32)
                                  : (pB + offB[mt] + (gn - SW) * 32);
        as[KS % PF][mt] = ldg_sc(ap);
      }
    }
    kstep<KQ, SW, PF, KS + 1>(pA, pB, offA, offB, Wl, brow0, brow1, base, as, acc);
  }
}

template<int KQ, int SW, int PF>
__device__ __attribute__((always_inline)) inline
void kloop(const u16* __restrict__ pA, const u16* __restrict__ pB,
           const int4v& offA, const int4v& offB, const u16* __restrict__ Wl,
           int brow0, int brow1, int wv, float4v (&acc)[4][2]) {
  static_assert(PF <= KQ, "prefetch depth > trip count");
  const int base = wv * KQ;
  short8 as[PF][4];
#pragma unroll
  for (int p = 0; p < PF; ++p) {
    const int gks = base + p;
#pragma unroll
    for (int mt = 0; mt < 4; ++mt) {
      const u16* ap = (gks < SW) ? (pA + offA[mt] + gks * 32)
                                 : (pB + offB[mt] + (gks - SW) * 32);
      as[p][mt] = ldg_sc(ap);
    }
  }
  kstep<KQ, SW, PF, 0>(pA, pB, offA, offB, Wl, brow0, brow1, base, as, acc);
}

// ---------------- persistent LSTM kernel ----------------
// Blocks 0..127: layer0 (K=1280: [x_t | h0]); blocks 128..255: layer1 (K=2048: [h0_t | h1]).
// Global step s: layer0 does t=s (s<512), layer1 does t=s-1 (s>=1). 513 steps, barrier each.
__global__ void __launch_bounds__(256, 1)
lstm_persist(const u16* __restrict__ wp0, const u16* __restrict__ wp1,
             const u16* __restrict__ xb, u16* __restrict__ hb0, u16* __restrict__ hb1,
             const float* __restrict__ bc0, const float* __restrict__ bc1,
             const float* __restrict__ c0in, float* __restrict__ out,
             unsigned* __restrict__ bar) {
  extern __shared__ char smem[];
  u16* Wl = (u16*)smem;
  float* sc = (float*)(smem + SC_BYTE_OFF);   // 64 x 33 fp32 gate scratch

  const int b = blockIdx.x;
  const int layer = b >> 7;
  const int blk = b & 127;
  const int tid = threadIdx.x;
  const int lane = tid & 63;
  const int wv = tid >> 6;
  const int l15 = lane & 15;
  const int qd = lane >> 4;
  const int qd8 = qd * 8;

  const int K = layer ? 2048 : 1280;
  const int KP = K + 8;                       // +16B pad per row -> 2-way (free) LDS conflicts
  const u16* wsrc = layer ? (wp1 + blk * 32 * 2048) : (wp0 + blk * 32 * 1280);

  // load W slice into LDS (one-time, normal cached loads)
  for (int q = 0; q < 32; ++q) {
    int k = tid * 8;
    if (k < K) *(short8*)&Wl[q * KP + k] = *(const short8*)&wsrc[q * K + k];
  }
  __syncthreads();

  float* out_y = out + OUT_Y_OFF;
  float* all_c = out + ALLC_OFF;
  float* h_n   = out + HN_OFF;
  float* c_n   = out + CN_OFF;

  // elementwise assignment: thread handles row mrow, col pair (col0, col0+1)
  const int mrow = wv * 16 + (lane >> 2);     // 0..63
  const int cp2  = (lane & 3) * 2;            // local col 0,2,4,6
  const int col0 = blk * 8 + cp2;
  const float* bcl = layer ? bc1 : bc0;
  const float bi0 = bcl[col0],        bi1 = bcl[col0 + 1];
  const float bf0 = bcl[1024 + col0], bf1 = bcl[1025 + col0];
  const float bg0 = bcl[2048 + col0], bg1 = bcl[2049 + col0];
  const float bo0 = bcl[3072 + col0], bo1 = bcl[3073 + col0];
  float cs0 = c0in[layer * 65536 + mrow * 1024 + col0];
  float cs1 = c0in[layer * 65536 + mrow * 1024 + col0 + 1];

  int4v offA, offB;
#pragma unroll
  for (int mt = 0; mt < 4; ++mt) {
    int row = mt * 16 + l15;
    offA[mt] = layer ? (row * 1024 + qd8) : (row * 256 + qd8);
    offB[mt] = row * 1024 + qd8;
  }
  const int brow0 = l15 * KP + qd8;
  const int brow1 = (16 + l15) * KP + qd8;
  const int gi = b >> 4;

  for (int s = 0; s <= 512; ++s) {
    const bool act = layer ? (s >= 1) : (s < 512);
    const int t = layer ? (s - 1) : s;

    if (act) for (int i = tid; i < 2112; i += 256) sc[i] = 0.0f;
    __syncthreads();

    if (act) {
      const u16* pA; const u16* pB;
      if (layer == 0) { pA = xb + t * 16384;               pB = hb0 + (t & 1) * 65536; }
      else            { pA = hb0 + ((t + 1) & 1) * 65536;  pB = hb1 + (t & 1) * 65536; }

      float4v acc[4][2];
      float4v zz = {0.0f, 0.0f, 0.0f, 0.0f};
#pragma unroll
      for (int mt = 0; mt < 4; ++mt) { acc[mt][0] = zz; acc[mt][1] = zz; }

      if (layer == 0) kloop<10, 8, 10>(pA, pB, offA, offB, Wl, brow0, brow1, wv, acc);
      else            kloop<16, 32, 10>(pA, pB, offA, offB, Wl, brow0, brow1, wv, acc);

      // combine k-quarter partials: D[m][q], m = mt*16 + qd*4 + r, q = nt*16 + l15
#pragma unroll
      for (int mt = 0; mt < 4; ++mt)
#pragma unroll
        for (int nt = 0; nt < 2; ++nt)
#pragma unroll
          for (int r = 0; r < 4; ++r)
            atomicAdd(&sc[(mt * 16 + qd * 4 + r) * 33 + nt * 16 + l15], acc[mt][nt][r]);
    }
    __syncthreads();

    if (act) {
      u16* hnx = (layer ? hb1 : hb0) + ((t + 1) & 1) * 65536;
      const float* srow = sc + mrow * 33;
      float gI0 = srow[cp2]          + bi0;
      float gI1 = srow[cp2 + 1]      + bi1;
      float gF0 = srow[8 + cp2]      + bf0;
      float gF1 = srow[9 + cp2]      + bf1;
      float gG0 = srow[16 + cp2]     + bg0;
      float gG1 = srow[17 + cp2]     + bg1;
      float gO0 = srow[24 + cp2]     + bo0;
      float gO1 = srow[25 + cp2]     + bo1;
      float cn0 = sigf(gF0) * cs0 + sigf(gI0) * tanh_fast(gG0);
      float cn1 = sigf(gF1) * cs1 + sigf(gI1) * tanh_fast(gG1);
      float hn0 = sigf(gO0) * tanh_fast(cn0);
      float hn1 = sigf(gO1) * tanh_fast(cn1);
      cs0 = cn0; cs1 = cn1;

      // h broadcast: packed 2xbf16, write-through to coherence point
      u32 hv = (u32)f2b(hn0) | ((u32)f2b(hn1) << 16);
      stg_sc((u32*)(hnx + mrow * 1024 + col0), hv);

      const int oidx = mrow * 1024 + col0;
      if (layer == 0) {
        __builtin_nontemporal_store(cn0, &all_c[t * 131072 + oidx]);
        __builtin_nontemporal_store(cn1, &all_c[t * 131072 + oidx + 1]);
      } else {
        __builtin_nontemporal_store(cn0, &all_c[t * 131072 + 65536 + oidx]);
        __builtin_nontemporal_store(cn1, &all_c[t * 131072 + 65536 + oidx + 1]);
        __builtin_nontemporal_store(hn0, &out_y[t * 65536 + oidx]);
        __builtin_nontemporal_store(hn1, &out_y[t * 65536 + oidx + 1]);
      }
      if (t == 511) {
        __builtin_nontemporal_store(hn0, &h_n[layer * 65536 + oidx]);
        __builtin_nontemporal_store(hn1, &h_n[layer * 65536 + oidx + 1]);
        __builtin_nontemporal_store(cn0, &c_n[layer * 65536 + oidx]);
        __builtin_nontemporal_store(cn1, &c_n[layer * 65536 + oidx + 1]);
      }
    }
    grid_barrier(bar, gi);
  }
}

// ---------------- launch ----------------
extern "C" void kernel_launch(void* const* d_in, const int* in_sizes, int n_in,
                              void* d_out, int out_size, void* d_ws, size_t ws_size,
                              hipStream_t stream) {
  (void)in_sizes; (void)n_in; (void)out_size; (void)ws_size;
  const float* x     = (const float*)d_in[0];
  const float* h0i   = (const float*)d_in[1];
  const float* c0i   = (const float*)d_in[2];
  const float* w_ih0 = (const float*)d_in[3];
  const float* w_hh0 = (const float*)d_in[4];
  const float* b_ih0 = (const float*)d_in[5];
  const float* b_hh0 = (const float*)d_in[6];
  const float* w_ih1 = (const float*)d_in[7];
  const float* w_hh1 = (const float*)d_in[8];
  const float* b_ih1 = (const float*)d_in[9];
  const float* b_hh1 = (const float*)d_in[10];
  float* out = (float*)d_out;
  char* ws = (char*)d_ws;

  u16* wp0 = (u16*)(ws + WP0_OFF);
  u16* wp1 = (u16*)(ws + WP1_OFF);
  u16* xb  = (u16*)(ws + XB_OFF);
  u16* hb0 = (u16*)(ws + HB0_OFF);
  u16* hb1 = (u16*)(ws + HB1_OFF);
  float* bc0 = (float*)(ws + BC0_OFF);
  float* bc1 = (float*)(ws + BC1_OFF);
  unsigned* bar = (unsigned*)(ws + BAR_OFF);

  pack_w0<<<dim3(5, 32, 128), 256, 0, stream>>>(w_ih0, w_hh0, wp0);
  pack_w1<<<dim3(8, 32, 128), 256, 0, stream>>>(w_ih1, w_hh1, wp1);
  prep_misc<<<33316, 256, 0, stream>>>(x, h0i, b_ih0, b_hh0, b_ih1, b_hh1,
                                       xb, hb0, hb1, bc0, bc1, bar);

  hipFuncSetAttribute((const void*)lstm_persist,
                      hipFuncAttributeMaxDynamicSharedMemorySize, LDS_BYTES);
  lstm_persist<<<256, 256, LDS_BYTES, stream>>>(wp0, wp1, xb, hb0, hb1,
                                                bc0, bc1, c0i, out, bar);
}

// Round 2
// 10759.554 us; speedup vs baseline: 2.9775x; 1.0132x over previous
//
#include <hip/hip_runtime.h>

// LSTMx: 2-layer LSTM, L=512, N=64, IN=256, H=1024. fp32 in/out, bf16 MFMA compute.
// R2: decoupled-layer scheduling. Layer0 (blocks 0..127) and layer1 (128..255) each
// run their own 128-block two-level barrier; cross-layer deps via monotonic progress
// counters (gen0/gen1) with per-group broadcast copies. hb0 is 4-deep so L0 can run
// up to 3 steps ahead (WAR gated on gen1 >= t-3, rarely blocking). Output stores are
// explicit `nt` asm stores left in flight across the barrier (arrive after vmcnt(OUT),
// not vmcnt(0)); the K-loop's in-order hand-counted vmcnt waits absorb them safely.
// sc gate scratch is re-zeroed by its reader thread (no post-barrier zero phase).
// h transport unchanged from R1: sc0 sc1 write-through stores + sc0 sc1 L2-bypass loads.

typedef unsigned short u16;
typedef unsigned int u32;
typedef __attribute__((ext_vector_type(8))) short short8;
typedef __attribute__((ext_vector_type(2))) float float2v;
typedef __attribute__((ext_vector_type(4))) float float4v;
typedef __attribute__((ext_vector_type(4))) int int4v;

// ---- workspace layout (bytes) ----
#define WP0_OFF   0u               // 128*32*1280*2 = 10485760  (layer0 packed W, bf16)
#define WP1_OFF   10485760u        // 128*32*2048*2 = 16777216  (layer1 packed W)
#define XB_OFF    27262976u        // 512*64*256*2  = 16777216  (x in bf16)
#define HB0_OFF   44040192u        // 4*64*1024*2   = 524288    (h0 quad buffer, bf16)
#define HB1_OFF   44564480u        // 2*64*1024*2   = 262144    (h1 double buffer)
#define BC0_OFF   44826624u        // 4096*4
#define BC1_OFF   44843008u        // 4096*4
#define BAR_OFF   44859392u        // 2048*4  (barrier/progress state)

// ---- output offsets (floats) ----
#define OUT_Y_OFF 0
#define ALLC_OFF  33554432
#define HN_OFF    100663296
#define CN_OFF    100794368

// LDS: W slice (max 32 rows * (2048+8) * 2B = 131584) + gate scratch 64*33*4 = 8448
#define SC_BYTE_OFF 131584
#define LDS_BYTES   140032

// ---- bar u32 indices ----
#define ARR0 0      // L0 group arrival counters, g*32, g=0..7
#define ARR1 256    // L1 group arrival counters
#define L2C0 512    // L0 level-2 counter
#define L2C1 544    // L1 level-2 counter
#define GEN0 576    // L0 gen copies (per group), g*32
#define GEN1 896    // L1 gen copies
#define PUB0 1216   // gen0 copies polled by L1 groups
#define PUB1 1536   // gen1 copies polled by L0 groups

__device__ inline u16 f2b(float v) {  // fp32 -> bf16 RTNE (finite inputs)
  union { float f; unsigned u; } a; a.f = v;
  unsigned r = a.u + 0x7FFFu + ((a.u >> 16) & 1u);
  return (u16)(r >> 16);
}

__device__ inline float sigf(float x) { return 1.0f / (1.0f + __expf(-x)); }
__device__ inline float tanh_fast(float x) { return 1.0f - 2.0f / (1.0f + __expf(2.0f * x)); }

// Coherence-point (L1+L2 bypass) 16B load / 4B store.
__device__ __attribute__((always_inline)) inline short8 ldg_sc(const u16* p) {
  short8 r;
  asm volatile("global_load_dwordx4 %0, %1, off sc0 sc1" : "=v"(r) : "v"(p));
  return r;
}
__device__ __attribute__((always_inline)) inline void stg_sc(u32* p, u32 v) {
  asm volatile("global_store_dword %0, %1, off sc0 sc1" : : "v"(p), "v"(v) : "memory");
}
// Nontemporal 8B output store (kept as asm so outstanding-store counts are exact).
__device__ __attribute__((always_inline)) inline void stg_nt2(float* p, float a, float b) {
  float2v v; v.x = a; v.y = b;
  asm volatile("global_store_dwordx2 %0, %1, off nt" : : "v"(p), "v"(v) : "memory");
}

template<int N>
__device__ __attribute__((always_inline)) inline void wait_vm() {
  static_assert(N >= 0 && N <= 36, "bad vmcnt");
  if constexpr (N == 0)  asm volatile("s_waitcnt vmcnt(0)" ::: "memory");
  if constexpr (N == 1)  asm volatile("s_waitcnt vmcnt(1)" ::: "memory");
  if constexpr (N == 2)  asm volatile("s_waitcnt vmcnt(2)" ::: "memory");
  if constexpr (N == 4)  asm volatile("s_waitcnt vmcnt(4)" ::: "memory");
  if constexpr (N == 8)  asm volatile("s_waitcnt vmcnt(8)" ::: "memory");
  if constexpr (N == 12) asm volatile("s_waitcnt vmcnt(12)" ::: "memory");
  if constexpr (N == 16) asm volatile("s_waitcnt vmcnt(16)" ::: "memory");
  if constexpr (N == 20) asm volatile("s_waitcnt vmcnt(20)" ::: "memory");
  if constexpr (N == 24) asm volatile("s_waitcnt vmcnt(24)" ::: "memory");
  if constexpr (N == 28) asm volatile("s_waitcnt vmcnt(28)" ::: "memory");
  if constexpr (N == 32) asm volatile("s_waitcnt vmcnt(32)" ::: "memory");
  if constexpr (N == 36) asm volatile("s_waitcnt vmcnt(36)" ::: "memory");
}

// ---------------- prep kernels ----------------

__global__ void pack_w0(const float* __restrict__ w_ih, const float* __restrict__ w_hh,
                        u16* __restrict__ wp) {
  int k = blockIdx.x * 256 + threadIdx.x;   // 0..1279
  int q = blockIdx.y;                       // 0..31
  int b = blockIdx.z;                       // 0..127
  int g = q >> 3, jj = q & 7;
  int r = g * 1024 + b * 8 + jj;
  float v = (k < 256) ? w_ih[r * 256 + k] : w_hh[r * 1024 + (k - 256)];
  wp[(b * 32 + q) * 1280 + k] = f2b(v);
}

__global__ void pack_w1(const float* __restrict__ w_ih, const float* __restrict__ w_hh,
                        u16* __restrict__ wp) {
  int k = blockIdx.x * 256 + threadIdx.x;   // 0..2047
  int q = blockIdx.y;
  int b = blockIdx.z;
  int g = q >> 3, jj = q & 7;
  int r = g * 1024 + b * 8 + jj;
  float v = (k < 1024) ? w_ih[r * 1024 + k] : w_hh[r * 1024 + (k - 1024)];
  wp[(b * 32 + q) * 2048 + k] = f2b(v);
}

// x -> bf16; initial h0 -> hb0 buffer 3 (L0 at t=0 reads buffer (t-1)&3 = 3);
// initial h1 -> hb1 buffer 1 (L1 at t=0 reads buffer (t-1)&1 = 1); biases; bar zero.
__global__ void prep_misc(const float* __restrict__ x, const float* __restrict__ h0,
                          const float* __restrict__ bih0, const float* __restrict__ bhh0,
                          const float* __restrict__ bih1, const float* __restrict__ bhh1,
                          u16* __restrict__ xb, u16* __restrict__ hb0, u16* __restrict__ hb1,
                          float* __restrict__ bc0, float* __restrict__ bc1,
                          unsigned* __restrict__ bar) {
  int i = blockIdx.x * 256 + threadIdx.x;
  if (i < 8388608) { xb[i] = f2b(x[i]); return; }
  i -= 8388608;
  if (i < 65536) { hb0[3 * 65536 + i] = f2b(h0[i]); return; }
  i -= 65536;
  if (i < 65536) { hb1[65536 + i] = f2b(h0[65536 + i]); return; }
  i -= 65536;
  if (i < 4096) { bc0[i] = bih0[i] + bhh0[i]; return; }
  i -= 4096;
  if (i < 4096) { bc1[i] = bih1[i] + bhh1[i]; return; }
  i -= 4096;
  if (i < 2048) bar[i] = 0u;
}

// ---------------- per-layer barrier (128 blocks = 8 groups of 16) ----------------
// Monotonic relaxed counters; no fences (h data is at the coherence point already,
// drained by the caller's vmcnt before arrival). Flipper broadcasts gen to 8 own-layer
// copies + 8 cross-layer progress copies; each leader polls only its group's line.
__device__ __attribute__((always_inline)) inline
void layer_barrier(unsigned* __restrict__ bar, int gi, unsigned step,
                   int arrBase, int l2Idx, int genBase, int pubBase) {
  __syncthreads();
  if (threadIdx.x == 0) {
    unsigned a = __hip_atomic_fetch_add(bar + arrBase + gi * 32, 1u,
                                        __ATOMIC_RELAXED, __HIP_MEMORY_SCOPE_AGENT);
    if ((a & 15u) == 15u) {
      unsigned r = __hip_atomic_fetch_add(bar + l2Idx, 1u,
                                          __ATOMIC_RELAXED, __HIP_MEMORY_SCOPE_AGENT);
      if ((r & 7u) == 7u) {
        unsigned v = step + 1u;
        for (int g = 0; g < 8; ++g)
          __hip_atomic_store(bar + genBase + g * 32, v, __ATOMIC_RELAXED, __HIP_MEMORY_SCOPE_AGENT);
        for (int g = 0; g < 8; ++g)
          __hip_atomic_store(bar + pubBase + g * 32, v, __ATOMIC_RELAXED, __HIP_MEMORY_SCOPE_AGENT);
      }
    }
    while ((int)(__hip_atomic_load(bar + genBase + gi * 32, __ATOMIC_RELAXED,
                                   __HIP_MEMORY_SCOPE_AGENT) - (step + 1u)) < 0)
      __builtin_amdgcn_s_sleep(1);
  }
  __syncthreads();
}

// leader polls a progress copy until >= need, then releases the block.
__device__ __attribute__((always_inline)) inline
void wait_pub(unsigned* __restrict__ bar, int idx, unsigned need) {
  if (threadIdx.x == 0) {
    while ((int)(__hip_atomic_load(bar + idx, __ATOMIC_RELAXED,
                                   __HIP_MEMORY_SCOPE_AGENT) - need) < 0)
      __builtin_amdgcn_s_sleep(1);
  }
  __syncthreads();
}

// ---------------- per-step GEMM K-loop ----------------
template<int KQ, int SW, int PF, int KS>
__device__ __attribute__((always_inline)) inline
void kstep(const u16* __restrict__ pA, const u16* __restrict__ pB,
           const int4v& offA, const int4v& offB, const u16* __restrict__ Wl,
           int brow0, int brow1, int base, short8 (&as)[PF][4], float4v (&acc)[4][2]) {
  if constexpr (KS < KQ) {
    const int gks = base + KS;
    short8 b0 = *(const short8*)&Wl[brow0 + gks * 32];
    short8 b1 = *(const short8*)&Wl[brow1 + gks * 32];
    constexpr int REM = KQ - 1 - KS;
    constexpr int W = 4 * (REM < (PF - 1) ? REM : (PF - 1));
    wait_vm<W>();                          // in-order vmcnt: slot-KS loads complete
    __builtin_amdgcn_sched_barrier(0);     // rule #18
#pragma unroll
    for (int mt = 0; mt < 4; ++mt) {
      acc[mt][0] = __builtin_amdgcn_mfma_f32_16x16x32_bf16(as[KS % PF][mt], b0, acc[mt][0], 0, 0, 0);
      acc[mt][1] = __builtin_amdgcn_mfma_f32_16x16x32_bf16(as[KS % PF][mt], b1, acc[mt][1], 0, 0, 0);
    }
    if constexpr (KS + PF < KQ) {
      const int gn = base + KS + PF;
#pragma unroll
      for (int mt = 0; mt < 4; ++mt) {
        const u16* ap = (gn < SW) ? (pA + offA[mt] + gn * 32)
                                  : (pB + offB[mt] + (gn - SW) * 32);
        as[KS % PF][mt] = ldg_sc(ap);
      }
    }
    kstep<KQ, SW, PF, KS + 1>(pA, pB, offA, offB, Wl, brow0, brow1, base, as, acc);
  }
}

template<int KQ, int SW, int PF>
__device__ __attribute__((always_inline)) inline
void kloop(const u16* __restrict__ pA, const u16* __restrict__ pB,
           const int4v& offA, const int4v& offB, const u16* __restrict__ Wl,
           int brow0, int brow1, int wv, float4v (&acc)[4][2]) {
  static_assert(PF <= KQ, "prefetch depth > trip count");
  const int base = wv * KQ;
  short8 as[PF][4];
#pragma unroll
  for (int p = 0; p < PF; ++p) {
    const int gks = base + p;
#pragma unroll
    for (int mt = 0; mt < 4; ++mt) {
      const u16* ap = (gks < SW) ? (pA + offA[mt] + gks * 32)
                                 : (pB + offB[mt] + (gks - SW) * 32);
      as[p][mt] = ldg_sc(ap);
    }
  }
  kstep<KQ, SW, PF, 0>(pA, pB, offA, offB, Wl, brow0, brow1, base, as, acc);
}

// ---------------- per-layer persistent loop ----------------
template<int LAYER>
__device__ __attribute__((always_inline)) inline
void run_layer(const u16* __restrict__ wp, const u16* __restrict__ xb,
               u16* __restrict__ hb0, u16* __restrict__ hb1,
               const float* __restrict__ bc, const float* __restrict__ c0in,
               float* __restrict__ out, unsigned* __restrict__ bar,
               u16* Wl, float* sc, int blk) {
  constexpr int K   = LAYER ? 2048 : 1280;
  constexpr int KP  = K + 8;
  constexpr int KQ  = LAYER ? 16 : 10;
  constexpr int SW  = LAYER ? 32 : 8;
  constexpr int OUT = LAYER ? 2 : 1;       // nt output stores in flight at arrival

  const int tid = threadIdx.x;
  const int lane = tid & 63;
  const int wv = tid >> 6;
  const int l15 = lane & 15;
  const int qd = lane >> 4;
  const int qd8 = qd * 8;
  const int gi = blk >> 4;

  // one-time: W slice -> LDS; zero gate scratch
  const u16* wsrc = wp + blk * 32 * K;
  for (int q = 0; q < 32; ++q) {
    int k = tid * 8;
    if (k < K) *(short8*)&Wl[q * KP + k] = *(const short8*)&wsrc[q * K + k];
  }
  for (int i = tid; i < 2112; i += 256) sc[i] = 0.0f;
  __syncthreads();

  float* out_y = out + OUT_Y_OFF;
  float* all_c = out + ALLC_OFF;
  float* h_n   = out + HN_OFF;
  float* c_n   = out + CN_OFF;

  const int mrow = wv * 16 + (lane >> 2);     // 0..63
  const int cp2  = (lane & 3) * 2;            // 0,2,4,6
  const int col0 = blk * 8 + cp2;
  const float bi0 = bc[col0],        bi1 = bc[col0 + 1];
  const float bf0 = bc[1024 + col0], bf1 = bc[1025 + col0];
  const float bg0 = bc[2048 + col0], bg1 = bc[2049 + col0];
  const float bo0 = bc[3072 + col0], bo1 = bc[3073 + col0];
  float cs0 = c0in[LAYER * 65536 + mrow * 1024 + col0];
  float cs1 = c0in[LAYER * 65536 + mrow * 1024 + col0 + 1];

  int4v offA, offB;
#pragma unroll
  for (int mt = 0; mt < 4; ++mt) {
    int row = mt * 16 + l15;
    offA[mt] = LAYER ? (row * 1024 + qd8) : (row * 256 + qd8);
    offB[mt] = row * 1024 + qd8;
  }
  const int brow0 = l15 * KP + qd8;
  const int brow1 = (16 + l15) * KP + qd8;

  for (int t = 0; t < 512; ++t) {
    // cross-layer pre-waits
    if constexpr (LAYER == 0) {
      if (t >= 4) wait_pub(bar, PUB1 + gi * 32, (unsigned)(t - 3));  // WAR: L1 done t-4
    } else {
      wait_pub(bar, PUB0 + gi * 32, (unsigned)(t + 1));              // RAW: h0(t) ready
    }

    const u16* pA; const u16* pB;
    if constexpr (LAYER == 0) { pA = xb + t * 16384;              pB = hb0 + ((t + 3) & 3) * 65536; }
    else                      { pA = hb0 + (t & 3) * 65536;       pB = hb1 + ((t + 1) & 1) * 65536; }

    float4v acc[4][2];
    float4v zz = {0.0f, 0.0f, 0.0f, 0.0f};
#pragma unroll
    for (int mt = 0; mt < 4; ++mt) { acc[mt][0] = zz; acc[mt][1] = zz; }

    kloop<KQ, SW, 10>(pA, pB, offA, offB, Wl, brow0, brow1, wv, acc);

    // combine k-quarter partials into sc (zeroed by reader threads last step)
#pragma unroll
    for (int mt = 0; mt < 4; ++mt)
#pragma unroll
      for (int nt = 0; nt < 2; ++nt)
#pragma unroll
        for (int r = 0; r < 4; ++r)
          atomicAdd(&sc[(mt * 16 + qd * 4 + r) * 33 + nt * 16 + l15], acc[mt][nt][r]);
    __syncthreads();

    // elementwise: read own 8 gate cells, immediately re-zero them (each cell has
    // exactly one reader, so no cross-thread hazard; barrier orders vs next step).
    float* srw = sc + mrow * 33;
    float gI0 = srw[cp2]      + bi0;  float gI1 = srw[cp2 + 1]  + bi1;
    float gF0 = srw[8 + cp2]  + bf0;  float gF1 = srw[9 + cp2]  + bf1;
    float gG0 = srw[16 + cp2] + bg0;  float gG1 = srw[17 + cp2] + bg1;
    float gO0 = srw[24 + cp2] + bo0;  float gO1 = srw[25 + cp2] + bo1;
    srw[cp2] = 0.f; srw[cp2 + 1] = 0.f; srw[8 + cp2] = 0.f; srw[9 + cp2] = 0.f;
    srw[16 + cp2] = 0.f; srw[17 + cp2] = 0.f; srw[24 + cp2] = 0.f; srw[25 + cp2] = 0.f;

    float cn0 = sigf(gF0) * cs0 + sigf(gI0) * tanh_fast(gG0);
    float cn1 = sigf(gF1) * cs1 + sigf(gI1) * tanh_fast(gG1);
    float hn0 = sigf(gO0) * tanh_fast(cn0);
    float hn1 = sigf(gO1) * tanh_fast(cn1);
    cs0 = cn0; cs1 = cn1;

    // h broadcast FIRST (must complete before arrival), then nt outputs (may float).
    u16* hnx = LAYER ? (hb1 + (t & 1) * 65536) : (hb0 + (t & 3) * 65536);
    u32 hv = (u32)f2b(hn0) | ((u32)f2b(hn1) << 16);
    stg_sc((u32*)(hnx + mrow * 1024 + col0), hv);

    const int oidx = mrow * 1024 + col0;
    if constexpr (LAYER == 0) {
      stg_nt2(&all_c[t * 131072 + oidx], cn0, cn1);
    } else {
      stg_nt2(&all_c[t * 131072 + 65536 + oidx], cn0, cn1);
      stg_nt2(&out_y[t * 65536 + oidx], hn0, hn1);
    }
    if (t == 511) {
      stg_nt2(&h_n[LAYER * 65536 + oidx], hn0, hn1);
      stg_nt2(&c_n[LAYER * 65536 + oidx], cn0, cn1);
      wait_vm<0>();                       // final step: drain everything
    } else {
      wait_vm<OUT>();                     // h-store done; outputs still in flight
    }

    if constexpr (LAYER == 0) layer_barrier(bar, gi, (unsigned)t, ARR0, L2C0, GEN0, PUB0);
    else                      layer_barrier(bar, gi, (unsigned)t, ARR1, L2C1, GEN1, PUB1);
  }
}

__global__ void __launch_bounds__(256, 1)
lstm_persist(const u16* __restrict__ wp0, const u16* __restrict__ wp1,
             const u16* __restrict__ xb, u16* __restrict__ hb0, u16* __restrict__ hb1,
             const float* __restrict__ bc0, const float* __restrict__ bc1,
             const float* __restrict__ c0in, float* __restrict__ out,
             unsigned* __restrict__ bar) {
  extern __shared__ char smem[];
  u16* Wl = (u16*)smem;
  float* sc = (float*)(smem + SC_BYTE_OFF);

  const int b = blockIdx.x;
  const int blk = b & 127;
  if (b < 128) run_layer<0>(wp0, xb, hb0, hb1, bc0, c0in, out, bar, Wl, sc, blk);
  else         run_layer<1>(wp1, xb, hb0, hb1, bc1, c0in, out, bar, Wl, sc, blk);
}

// ---------------- launch ----------------
extern "C" void kernel_launch(void* const* d_in, const int* in_sizes, int n_in,
                              void* d_out, int out_size, void* d_ws, size_t ws_size,
                              hipStream_t stream) {
  (void)in_sizes; (void)n_in; (void)out_size; (void)ws_size;
  const float* x     = (const float*)d_in[0];
  const float* h0i   = (const float*)d_in[1];
  const float* c0i   = (const float*)d_in[2];
  const float* w_ih0 = (const float*)d_in[3];
  const float* w_hh0 = (const float*)d_in[4];
  const float* b_ih0 = (const float*)d_in[5];
  const float* b_hh0 = (const float*)d_in[6];
  const float* w_ih1 = (const float*)d_in[7];
  const float* w_hh1 = (const float*)d_in[8];
  const float* b_ih1 = (const float*)d_in[9];
  const float* b_hh1 = (const float*)d_in[10];
  float* out = (float*)d_out;
  char* ws = (char*)d_ws;

  u16* wp0 = (u16*)(ws + WP0_OFF);
  u16* wp1 = (u16*)(ws + WP1_OFF);
  u16* xb  = (u16*)(ws + XB_OFF);
  u16* hb0 = (u16*)(ws + HB0_OFF);
  u16* hb1 = (u16*)(ws + HB1_OFF);
  float* bc0 = (float*)(ws + BC0_OFF);
  float* bc1 = (float*)(ws + BC1_OFF);
  unsigned* bar = (unsigned*)(ws + BAR_OFF);

  pack_w0<<<dim3(5, 32, 128), 256, 0, stream>>>(w_ih0, w_hh0, wp0);
  pack_w1<<<dim3(8, 32, 128), 256, 0, stream>>>(w_ih1, w_hh1, wp1);
  prep_misc<<<33320, 256, 0, stream>>>(x, h0i, b_ih0, b_hh0, b_ih1, b_hh1,
                                       xb, hb0, hb1, bc0, bc1, bar);

  hipFuncSetAttribute((const void*)lstm_persist,
                      hipFuncAttributeMaxDynamicSharedMemorySize, LDS_BYTES);
  lstm_persist<<<256, 256, LDS_BYTES, stream>>>(wp0, wp1, xb, hb0, hb1,
                                                bc0, bc1, c0i, out, bar);
}